// Round 4
// baseline (449.652 us; speedup 1.0000x reference)
//
#include <hip/hip_runtime.h>

// PolarConv via MFMA. Query q <-> edges [16q,16q+16) <-> one 16x16 tile.
// v4: 2-deep software-pipelined grid-stride loop (gathers for q+S and
// coalesced loads for q+2S issued before computing q), with the big constant
// tables (W3 transposed->bf16, b3) staged once per block into LDS and read
// per query as conflict-free ds_read_b128 with immediate offsets.
// No atomics; segment-sum = 4-stage butterfly over the 16 edge-lanes.

constexpr int THREADS = 256;
constexpr int NBLOCKS = 2048;

typedef __attribute__((ext_vector_type(8))) short short8;   // 8 bf16
typedef __attribute__((ext_vector_type(4))) float floatx4;

static __device__ inline short f2bf(float x) {
  __bf16 b = (__bf16)x;
  return __builtin_bit_cast(short, b);
}

__global__ __launch_bounds__(THREADS, 3) void polarconv_mfma4(
    const float* __restrict__ feats,   // [N,16]
    const float* __restrict__ xyz,     // [N,3]
    const int*   __restrict__ nbr,     // [E]
    const float* __restrict__ dist,    // [E]
    const float* __restrict__ W1,      // [4,32]
    const float* __restrict__ b1,      // [32]
    const float* __restrict__ W2,      // [32,32]
    const float* __restrict__ b2,      // [32]
    const float* __restrict__ W3,      // [32,256]
    const float* __restrict__ b3,      // [256]
    float* __restrict__ out,           // [Nq,16]
    int Nq)
{
  // W3 as bf16, laid out [t][r16][g][j] so lane (r16,g) reads its short8
  // A-fragment for M-tile t at flat = ((t*16+r16)*4+g)*8 + j.
  __shared__ alignas(16) short sBU[8192];   // 16 KB
  __shared__ alignas(16) float sB3[256];    // 1 KB

  const int tid  = threadIdx.x;
  const int lane = tid & 63;
  const int r16  = lane & 15;   // edge slot within query tile
  const int g    = lane >> 4;   // k-chunk group

  for (int i = tid; i < 8192; i += THREADS) {
    int j = i & 7, gg = (i >> 3) & 3, rr = (i >> 5) & 15, tt = i >> 9;
    int h = 4 * gg + (j & 3) + 16 * (j >> 2);   // hperm: lane's h2 C-frag dims
    sBU[i] = f2bf(W3[h * 256 + tt * 16 + rr]);
  }
  sB3[tid] = b3[tid];           // THREADS == 256
  __syncthreads();

  // ---- per-lane weight fragments (small, stay in VGPRs) ----
  float w1v0[8], w1v1[8], w1v2[8], w1v3[8], b1v[8];
#pragma unroll
  for (int j = 0; j < 8; ++j) {
    w1v0[j] = W1[0 * 32 + 8 * g + j];
    w1v1[j] = W1[1 * 32 + 8 * g + j];
    w1v2[j] = W1[2 * 32 + 8 * g + j];
    w1v3[j] = W1[3 * 32 + 8 * g + j];
    b1v[j]  = b1[8 * g + j];
  }
  short8 a2[2];                 // swapped-L2 A-frags: A[m=r16+16mt, k=8g+j]=W2[k*32+m]
#pragma unroll
  for (int mt = 0; mt < 2; ++mt)
#pragma unroll
    for (int j = 0; j < 8; ++j)
      a2[mt][j] = f2bf(W2[(8 * g + j) * 32 + r16 + 16 * mt]);
  float b2lo[4], b2hi[4];
#pragma unroll
  for (int r = 0; r < 4; ++r) {
    b2lo[r] = b2[4 * g + r];
    b2hi[r] = b2[16 + 4 * g + r];
  }

  const short8* bup = reinterpret_cast<const short8*>(sBU) + (r16 * 4 + g);
  const float4* b3p = reinterpret_cast<const float4*>(sB3) + g;

  const int wid = blockIdx.x * (THREADS / 64) + (tid >> 6);
  const int S   = NBLOCKS * (THREADS / 64);
  int q = wid;
  if (q >= Nq) return;

  // ---------------- pipeline prologue ----------------
  int   nbA, nbB;
  float dA, dB, qxA, qyA, qzA, qxB, qyB, qzB;
  float nxA, nyA, nzA;
  float fA[16];
  {
    const int eA = q * 16 + r16;
    nbA = nbr[eA];
    dA  = dist[eA];
    qxA = xyz[3 * q]; qyA = xyz[3 * q + 1]; qzA = xyz[3 * q + 2];
    nxA = xyz[3 * nbA]; nyA = xyz[3 * nbA + 1]; nzA = xyz[3 * nbA + 2];
    const float4* fp = reinterpret_cast<const float4*>(feats + (size_t)nbA * 16);
    float4 v0 = fp[0], v1 = fp[1], v2 = fp[2], v3 = fp[3];
    fA[0]=v0.x; fA[1]=v0.y; fA[2]=v0.z; fA[3]=v0.w;
    fA[4]=v1.x; fA[5]=v1.y; fA[6]=v1.z; fA[7]=v1.w;
    fA[8]=v2.x; fA[9]=v2.y; fA[10]=v2.z; fA[11]=v2.w;
    fA[12]=v3.x; fA[13]=v3.y; fA[14]=v3.z; fA[15]=v3.w;

    const int q1  = q + S;
    const int q1c = (q1 < Nq) ? q1 : q;
    const int eB  = q1c * 16 + r16;
    nbB = nbr[eB];
    dB  = dist[eB];
    qxB = xyz[3 * q1c]; qyB = xyz[3 * q1c + 1]; qzB = xyz[3 * q1c + 2];
  }

  // ---------------- main pipelined loop ----------------
  for (; q < Nq; q += S) {
    // issue gathers for q+S (nbB arrived during previous compute)
    float nxB = xyz[3 * nbB], nyB = xyz[3 * nbB + 1], nzB = xyz[3 * nbB + 2];
    float fB[16];
    {
      const float4* fp = reinterpret_cast<const float4*>(feats + (size_t)nbB * 16);
      float4 v0 = fp[0], v1 = fp[1], v2 = fp[2], v3 = fp[3];
      fB[0]=v0.x; fB[1]=v0.y; fB[2]=v0.z; fB[3]=v0.w;
      fB[4]=v1.x; fB[5]=v1.y; fB[6]=v1.z; fB[7]=v1.w;
      fB[8]=v2.x; fB[9]=v2.y; fB[10]=v2.z; fB[11]=v2.w;
      fB[12]=v3.x; fB[13]=v3.y; fB[14]=v3.z; fB[15]=v3.w;
    }
    // issue coalesced loads for q+2S
    const int qn  = q + S;
    const int qnc = (qn < Nq) ? qn : q;
    const int q2  = q + 2 * S;
    const int q2c = (q2 < Nq) ? q2 : qnc;
    const int eC  = q2c * 16 + r16;
    int   nbC = nbr[eC];
    float dC  = dist[eC];
    float qxC = xyz[3 * q2c], qyC = xyz[3 * q2c + 1], qzC = xyz[3 * q2c + 2];

    // ---- compute current query (all A-data resident) ----
    const float rA  = sqrtf(dA + 1e-7f);
    const float inv = 1.0f / rA;
    const float p0 = rA;
    const float p1 = (nxA - qxA) * inv;
    const float p2 = (nzA - qzA) * inv;
    const float p3 = (nyA - qyA) * inv;

    short8 bh1;
#pragma unroll
    for (int j = 0; j < 8; ++j) {
      float a = b1v[j];
      a = fmaf(p0, w1v0[j], a);
      a = fmaf(p1, w1v1[j], a);
      a = fmaf(p2, w1v2[j], a);
      a = fmaf(p3, w1v3[j], a);
      bh1[j] = f2bf(fmaxf(a, 0.0f));
    }

    floatx4 z = {0.f, 0.f, 0.f, 0.f};
    floatx4 c0 = __builtin_amdgcn_mfma_f32_16x16x32_bf16(a2[0], bh1, z, 0, 0, 0);
    floatx4 c1 = __builtin_amdgcn_mfma_f32_16x16x32_bf16(a2[1], bh1, z, 0, 0, 0);

    short8 bh2;
#pragma unroll
    for (int r = 0; r < 4; ++r) {
      bh2[r]     = f2bf(fmaxf(c0[r] + b2lo[r], 0.0f));
      bh2[4 + r] = f2bf(fmaxf(c1[r] + b2hi[r], 0.0f));
    }

    float S0 = 0.f, S1 = 0.f, S2 = 0.f, S3 = 0.f;
#pragma unroll
    for (int t = 0; t < 16; ++t) {
      short8 bt = bup[t * 64];          // ds_read_b128, imm offset t*1024
      float4 bc = b3p[t * 4];           // ds_read_b128 broadcast, imm t*64
      floatx4 cc; cc[0] = bc.x; cc[1] = bc.y; cc[2] = bc.z; cc[3] = bc.w;
      floatx4 dd = __builtin_amdgcn_mfma_f32_16x16x32_bf16(bt, bh2, cc, 0, 0, 0);
      S0 = fmaf(fA[t], dd[0], S0);
      S1 = fmaf(fA[t], dd[1], S1);
      S2 = fmaf(fA[t], dd[2], S2);
      S3 = fmaf(fA[t], dd[3], S3);
    }

    // segment sum over the 16 edge-lanes (bits 0..3)
#pragma unroll
    for (int m = 1; m <= 8; m <<= 1) {
      S0 += __shfl_xor(S0, m, 64);
      S1 += __shfl_xor(S1, m, 64);
      S2 += __shfl_xor(S2, m, 64);
      S3 += __shfl_xor(S3, m, 64);
    }
    if (r16 == 0) {
      float4 v = {S0, S1, S2, S3};
      *reinterpret_cast<float4*>(out + (size_t)q * 16 + 4 * g) = v;
    }

    // rotate pipeline registers
    nbB = nbC; dA = dB; dB = dC;
    nxA = nxB; nyA = nyB; nzA = nzB;
    qxA = qxB; qyA = qyB; qzA = qzB;
    qxB = qxC; qyB = qyC; qzB = qzC;
#pragma unroll
    for (int i = 0; i < 16; ++i) fA[i] = fB[i];
  }
}

extern "C" void kernel_launch(void* const* d_in, const int* in_sizes, int n_in,
                              void* d_out, int out_size, void* d_ws, size_t ws_size,
                              hipStream_t stream) {
  const float* feats = (const float*)d_in[0];
  const float* xyz   = (const float*)d_in[1];
  const int*   nbr   = (const int*)d_in[2];
  // d_in[3] = neighbors_row_splits: uniform arange*16 for this problem
  const float* dist  = (const float*)d_in[4];
  const float* W1 = (const float*)d_in[5];
  const float* b1 = (const float*)d_in[6];
  const float* W2 = (const float*)d_in[7];
  const float* b2 = (const float*)d_in[8];
  const float* W3 = (const float*)d_in[9];
  const float* b3 = (const float*)d_in[10];
  float* out = (float*)d_out;

  const int Nq = in_sizes[3] - 1;

  polarconv_mfma4<<<NBLOCKS, THREADS, 0, stream>>>(
      feats, xyz, nbr, dist, W1, b1, W2, b2, W3, b3, out, Nq);
}

// Round 5
// 167.458 us; speedup vs baseline: 2.6852x; 2.6852x over previous
//
#include <hip/hip_runtime.h>

// PolarConv via MFMA. Query q <-> edges [16q,16q+16) <-> one 16x16 tile.
// v5 == v4 (2-deep software-pipelined grid-stride loop + W3/b3 constants in
// LDS) with ONE change: __launch_bounds__(256) without a min-waves arg.
// v4's (256,3) made the allocator target 6 waves/SIMD (84 VGPR) and spill the
// whole pipeline state to scratch (WRITE_SIZE 6MB->203MB, FETCH 76MB->1.4GB).
// No atomics; segment-sum = 4-stage butterfly over the 16 edge-lanes.

constexpr int THREADS = 256;
constexpr int NBLOCKS = 2048;

typedef __attribute__((ext_vector_type(8))) short short8;   // 8 bf16
typedef __attribute__((ext_vector_type(4))) float floatx4;

static __device__ inline short f2bf(float x) {
  __bf16 b = (__bf16)x;
  return __builtin_bit_cast(short, b);
}

__global__ __launch_bounds__(THREADS) void polarconv_mfma5(
    const float* __restrict__ feats,   // [N,16]
    const float* __restrict__ xyz,     // [N,3]
    const int*   __restrict__ nbr,     // [E]
    const float* __restrict__ dist,    // [E]
    const float* __restrict__ W1,      // [4,32]
    const float* __restrict__ b1,      // [32]
    const float* __restrict__ W2,      // [32,32]
    const float* __restrict__ b2,      // [32]
    const float* __restrict__ W3,      // [32,256]
    const float* __restrict__ b3,      // [256]
    float* __restrict__ out,           // [Nq,16]
    int Nq)
{
  // W3 as bf16, laid out [t][r16][g][j] so lane (r16,g) reads its short8
  // A-fragment for M-tile t at flat = ((t*16+r16)*4+g)*8 + j.
  __shared__ alignas(16) short sBU[8192];   // 16 KB
  __shared__ alignas(16) float sB3[256];    // 1 KB

  const int tid  = threadIdx.x;
  const int lane = tid & 63;
  const int r16  = lane & 15;   // edge slot within query tile
  const int g    = lane >> 4;   // k-chunk group

  for (int i = tid; i < 8192; i += THREADS) {
    int j = i & 7, gg = (i >> 3) & 3, rr = (i >> 5) & 15, tt = i >> 9;
    int h = 4 * gg + (j & 3) + 16 * (j >> 2);   // hperm: lane's h2 C-frag dims
    sBU[i] = f2bf(W3[h * 256 + tt * 16 + rr]);
  }
  sB3[tid] = b3[tid];           // THREADS == 256
  __syncthreads();

  // ---- per-lane weight fragments (small, stay in VGPRs) ----
  float w1v0[8], w1v1[8], w1v2[8], w1v3[8], b1v[8];
#pragma unroll
  for (int j = 0; j < 8; ++j) {
    w1v0[j] = W1[0 * 32 + 8 * g + j];
    w1v1[j] = W1[1 * 32 + 8 * g + j];
    w1v2[j] = W1[2 * 32 + 8 * g + j];
    w1v3[j] = W1[3 * 32 + 8 * g + j];
    b1v[j]  = b1[8 * g + j];
  }
  short8 a2[2];                 // swapped-L2 A-frags: A[m=r16+16mt, k=8g+j]=W2[k*32+m]
#pragma unroll
  for (int mt = 0; mt < 2; ++mt)
#pragma unroll
    for (int j = 0; j < 8; ++j)
      a2[mt][j] = f2bf(W2[(8 * g + j) * 32 + r16 + 16 * mt]);
  float b2lo[4], b2hi[4];
#pragma unroll
  for (int r = 0; r < 4; ++r) {
    b2lo[r] = b2[4 * g + r];
    b2hi[r] = b2[16 + 4 * g + r];
  }

  const short8* bup = reinterpret_cast<const short8*>(sBU) + (r16 * 4 + g);
  const float4* b3p = reinterpret_cast<const float4*>(sB3) + g;

  const int wid = blockIdx.x * (THREADS / 64) + (tid >> 6);
  const int S   = NBLOCKS * (THREADS / 64);
  int q = wid;
  if (q >= Nq) return;

  // ---------------- pipeline prologue ----------------
  int   nbA, nbB;
  float dA, dB, qxA, qyA, qzA, qxB, qyB, qzB;
  float nxA, nyA, nzA;
  float fA[16];
  {
    const int eA = q * 16 + r16;
    nbA = nbr[eA];
    dA  = dist[eA];
    qxA = xyz[3 * q]; qyA = xyz[3 * q + 1]; qzA = xyz[3 * q + 2];
    nxA = xyz[3 * nbA]; nyA = xyz[3 * nbA + 1]; nzA = xyz[3 * nbA + 2];
    const float4* fp = reinterpret_cast<const float4*>(feats + (size_t)nbA * 16);
    float4 v0 = fp[0], v1 = fp[1], v2 = fp[2], v3 = fp[3];
    fA[0]=v0.x; fA[1]=v0.y; fA[2]=v0.z; fA[3]=v0.w;
    fA[4]=v1.x; fA[5]=v1.y; fA[6]=v1.z; fA[7]=v1.w;
    fA[8]=v2.x; fA[9]=v2.y; fA[10]=v2.z; fA[11]=v2.w;
    fA[12]=v3.x; fA[13]=v3.y; fA[14]=v3.z; fA[15]=v3.w;

    const int q1  = q + S;
    const int q1c = (q1 < Nq) ? q1 : q;
    const int eB  = q1c * 16 + r16;
    nbB = nbr[eB];
    dB  = dist[eB];
    qxB = xyz[3 * q1c]; qyB = xyz[3 * q1c + 1]; qzB = xyz[3 * q1c + 2];
  }

  // ---------------- main pipelined loop ----------------
  for (; q < Nq; q += S) {
    // issue gathers for q+S (nbB arrived during previous compute)
    float nxB = xyz[3 * nbB], nyB = xyz[3 * nbB + 1], nzB = xyz[3 * nbB + 2];
    float fB[16];
    {
      const float4* fp = reinterpret_cast<const float4*>(feats + (size_t)nbB * 16);
      float4 v0 = fp[0], v1 = fp[1], v2 = fp[2], v3 = fp[3];
      fB[0]=v0.x; fB[1]=v0.y; fB[2]=v0.z; fB[3]=v0.w;
      fB[4]=v1.x; fB[5]=v1.y; fB[6]=v1.z; fB[7]=v1.w;
      fB[8]=v2.x; fB[9]=v2.y; fB[10]=v2.z; fB[11]=v2.w;
      fB[12]=v3.x; fB[13]=v3.y; fB[14]=v3.z; fB[15]=v3.w;
    }
    // issue coalesced loads for q+2S
    const int qn  = q + S;
    const int qnc = (qn < Nq) ? qn : q;
    const int q2  = q + 2 * S;
    const int q2c = (q2 < Nq) ? q2 : qnc;
    const int eC  = q2c * 16 + r16;
    int   nbC = nbr[eC];
    float dC  = dist[eC];
    float qxC = xyz[3 * q2c], qyC = xyz[3 * q2c + 1], qzC = xyz[3 * q2c + 2];

    // ---- compute current query (all A-data resident) ----
    const float rA  = sqrtf(dA + 1e-7f);
    const float inv = 1.0f / rA;
    const float p0 = rA;
    const float p1 = (nxA - qxA) * inv;
    const float p2 = (nzA - qzA) * inv;
    const float p3 = (nyA - qyA) * inv;

    short8 bh1;
#pragma unroll
    for (int j = 0; j < 8; ++j) {
      float a = b1v[j];
      a = fmaf(p0, w1v0[j], a);
      a = fmaf(p1, w1v1[j], a);
      a = fmaf(p2, w1v2[j], a);
      a = fmaf(p3, w1v3[j], a);
      bh1[j] = f2bf(fmaxf(a, 0.0f));
    }

    floatx4 z = {0.f, 0.f, 0.f, 0.f};
    floatx4 c0 = __builtin_amdgcn_mfma_f32_16x16x32_bf16(a2[0], bh1, z, 0, 0, 0);
    floatx4 c1 = __builtin_amdgcn_mfma_f32_16x16x32_bf16(a2[1], bh1, z, 0, 0, 0);

    short8 bh2;
#pragma unroll
    for (int r = 0; r < 4; ++r) {
      bh2[r]     = f2bf(fmaxf(c0[r] + b2lo[r], 0.0f));
      bh2[4 + r] = f2bf(fmaxf(c1[r] + b2hi[r], 0.0f));
    }

    float S0 = 0.f, S1 = 0.f, S2 = 0.f, S3 = 0.f;
#pragma unroll
    for (int t = 0; t < 16; ++t) {
      short8 bt = bup[t * 64];          // ds_read_b128, imm offset t*1024
      float4 bc = b3p[t * 4];           // ds_read_b128 broadcast, imm t*64
      floatx4 cc; cc[0] = bc.x; cc[1] = bc.y; cc[2] = bc.z; cc[3] = bc.w;
      floatx4 dd = __builtin_amdgcn_mfma_f32_16x16x32_bf16(bt, bh2, cc, 0, 0, 0);
      S0 = fmaf(fA[t], dd[0], S0);
      S1 = fmaf(fA[t], dd[1], S1);
      S2 = fmaf(fA[t], dd[2], S2);
      S3 = fmaf(fA[t], dd[3], S3);
    }

    // segment sum over the 16 edge-lanes (bits 0..3)
#pragma unroll
    for (int m = 1; m <= 8; m <<= 1) {
      S0 += __shfl_xor(S0, m, 64);
      S1 += __shfl_xor(S1, m, 64);
      S2 += __shfl_xor(S2, m, 64);
      S3 += __shfl_xor(S3, m, 64);
    }
    if (r16 == 0) {
      float4 v = {S0, S1, S2, S3};
      *reinterpret_cast<float4*>(out + (size_t)q * 16 + 4 * g) = v;
    }

    // rotate pipeline registers
    nbB = nbC; dA = dB; dB = dC;
    nxA = nxB; nyA = nyB; nzA = nzB;
    qxA = qxB; qyA = qyB; qzA = qzB;
    qxB = qxC; qyB = qyC; qzB = qzC;
#pragma unroll
    for (int i = 0; i < 16; ++i) fA[i] = fB[i];
  }
}

extern "C" void kernel_launch(void* const* d_in, const int* in_sizes, int n_in,
                              void* d_out, int out_size, void* d_ws, size_t ws_size,
                              hipStream_t stream) {
  const float* feats = (const float*)d_in[0];
  const float* xyz   = (const float*)d_in[1];
  const int*   nbr   = (const int*)d_in[2];
  // d_in[3] = neighbors_row_splits: uniform arange*16 for this problem
  const float* dist  = (const float*)d_in[4];
  const float* W1 = (const float*)d_in[5];
  const float* b1 = (const float*)d_in[6];
  const float* W2 = (const float*)d_in[7];
  const float* b2 = (const float*)d_in[8];
  const float* W3 = (const float*)d_in[9];
  const float* b3 = (const float*)d_in[10];
  float* out = (float*)d_out;

  const int Nq = in_sizes[3] - 1;

  polarconv_mfma5<<<NBLOCKS, THREADS, 0, stream>>>(
      feats, xyz, nbr, dist, W1, b1, W2, b2, W3, b3, out, Nq);
}

// Round 6
// 92.065 us; speedup vs baseline: 4.8840x; 1.8189x over previous
//
#include <hip/hip_runtime.h>

// PolarConv v6: round-3 skeleton (all tables in registers, no LDS) with
//  - layer-1 via MFMA (zero-padded W1 A-frags, b1 in C operand)  [-40 VGPR]
//  - b3 term via one MFMA (round-2 bb trick) instead of b3c table [-64 VGPR]
//  - b2 bias via C operand of the L2 MFMAs (no VALU adds)
//  - 1-deep prefetch of next {nbr, dist, center xyz} (5 regs; the f-gather
//    needs no pipelining: issued first, consumed last -> hidden under MFMA)
//  - segment-sum via DPP v_add (quad_perm xor1/xor2, row_ror:4/8) -> VALU
//    pipe, zero DS traffic. Target: 3 waves/SIMD instead of 2.

constexpr int THREADS = 256;
constexpr int NBLOCKS = 1536;

typedef __attribute__((ext_vector_type(8))) short short8;   // 8 bf16
typedef __attribute__((ext_vector_type(4))) float floatx4;

static __device__ inline short f2bf(float x) {
  __bf16 b = (__bf16)x;
  return __builtin_bit_cast(short, b);
}

// x += dpp_shuffled(x); CTRL: 0xB1 xor1, 0x4E xor2, 0x124 ror4, 0x128 ror8
template <int CTRL>
static __device__ inline float dpp_add(float x) {
  int y = __builtin_amdgcn_update_dpp(0, __builtin_bit_cast(int, x),
                                      CTRL, 0xF, 0xF, true);
  return x + __builtin_bit_cast(float, y);
}

static __device__ inline int hperm(int g, int j) {
  return 4 * g + (j & 3) + 16 * (j >> 2);   // C/D-frag row layout of 16x16 MFMA
}

__global__ __launch_bounds__(THREADS) void polarconv_v6(
    const float* __restrict__ feats,   // [N,16]
    const float* __restrict__ xyz,     // [N,3]
    const int*   __restrict__ nbr,     // [E]
    const float* __restrict__ dist,    // [E]
    const float* __restrict__ W1,      // [4,32]
    const float* __restrict__ b1,      // [32]
    const float* __restrict__ W2,      // [32,32]
    const float* __restrict__ b2,      // [32]
    const float* __restrict__ W3,      // [32,256]
    const float* __restrict__ b3,      // [256]
    float* __restrict__ out,           // [Nq,16]
    int Nq)
{
  const int tid  = threadIdx.x;
  const int lane = tid & 63;
  const int r16  = lane & 15;   // edge slot / A-row
  const int g    = lane >> 4;   // k-chunk group

  // ---------------- per-lane register fragments (loaded once) --------------
  // Stage-B A-frags: A[row=r16, k=8g+j] = W3[hperm(g,j), t*16+r16]
  short8 bu[16];
#pragma unroll
  for (int t = 0; t < 16; ++t)
#pragma unroll
    for (int j = 0; j < 8; ++j)
      bu[t][j] = f2bf(W3[hperm(g, j) * 256 + t * 16 + r16]);

  // L1 A-frags (K=4 zero-padded to 32): A[row=r16+16mt, k=8g+j] = W1[j, row] (g==0,j<4)
  short8 a1_0, a1_1;
#pragma unroll
  for (int j = 0; j < 8; ++j) {
    a1_0[j] = (g == 0 && j < 4) ? f2bf(W1[j * 32 + r16])      : (short)0;
    a1_1[j] = (g == 0 && j < 4) ? f2bf(W1[j * 32 + 16 + r16]) : (short)0;
  }
  // b1 as L1 C-operand: C[row=4g+r] / C[row=16+4g+r]
  floatx4 b1c0, b1c1;
#pragma unroll
  for (int r = 0; r < 4; ++r) { b1c0[r] = b1[4 * g + r]; b1c1[r] = b1[16 + 4 * g + r]; }

  // L2 A-frags over hperm'd k (bh1 slots carry h1[hperm(g,j)]):
  short8 a2_0, a2_1;
#pragma unroll
  for (int j = 0; j < 8; ++j) {
    a2_0[j] = f2bf(W2[hperm(g, j) * 32 + r16]);
    a2_1[j] = f2bf(W2[hperm(g, j) * 32 + 16 + r16]);
  }
  // b2 as L2 C-operand
  floatx4 b2c0, b2c1;
#pragma unroll
  for (int r = 0; r < 4; ++r) { b2c0[r] = b2[4 * g + r]; b2c1[r] = b2[16 + 4 * g + r]; }

  // b3 A-frag (K=16 zero-padded): A[row=r16, k=8g+j] = b3[(8g+j)*16 + r16] (g<2)
  short8 bb;
#pragma unroll
  for (int j = 0; j < 8; ++j)
    bb[j] = (g < 2) ? f2bf(b3[(8 * g + j) * 16 + r16]) : (short)0;

  const int wid = blockIdx.x * (THREADS / 64) + (tid >> 6);
  const int S   = NBLOCKS * (THREADS / 64);
  int q = wid;
  if (q >= Nq) return;

  // prefetch state for iteration q
  int   nbN;
  float dN, cxN, cyN, czN;
  {
    const int e = q * 16 + r16;
    nbN = nbr[e];
    dN  = dist[e];
    cxN = xyz[3 * q]; cyN = xyz[3 * q + 1]; czN = xyz[3 * q + 2];
  }

  const floatx4 z4 = {0.f, 0.f, 0.f, 0.f};

  for (; q < Nq; q += S) {
    const int   nbA = nbN;
    const float dA  = dN, cx = cxN, cy = cyN, cz = czN;

    // issue current gathers (f consumed last -> latency hidden under MFMAs)
    const float nx = xyz[3 * nbA], ny = xyz[3 * nbA + 1], nz = xyz[3 * nbA + 2];
    const float4* fp = reinterpret_cast<const float4*>(feats + (size_t)nbA * 16);
    float4 v0 = fp[0], v1 = fp[1], v2 = fp[2], v3 = fp[3];

    // prefetch next iteration's {nbr, dist, center}
    {
      const int qn  = q + S;
      const int qnc = (qn < Nq) ? qn : q;
      const int e2  = qnc * 16 + r16;
      nbN = nbr[e2];
      dN  = dist[e2];
      cxN = xyz[3 * qnc]; cyN = xyz[3 * qnc + 1]; czN = xyz[3 * qnc + 2];
    }

    // ---- polar (f32) ----
    const float rr  = sqrtf(dA + 1e-7f);
    const float inv = 1.0f / rr;
    const float p0 = rr;
    const float p1 = (nx - cx) * inv;
    const float p2 = (nz - cz) * inv;
    const float p3 = (ny - cy) * inv;

    // L1 B-frag: B[k=8g+j, n=r16] = polar[k] (k<4 -> g==0 lanes only)
    short8 bp;
    bp[0] = (g == 0) ? f2bf(p0) : (short)0;
    bp[1] = (g == 0) ? f2bf(p1) : (short)0;
    bp[2] = (g == 0) ? f2bf(p2) : (short)0;
    bp[3] = (g == 0) ? f2bf(p3) : (short)0;
    bp[4] = 0; bp[5] = 0; bp[6] = 0; bp[7] = 0;

    // ---- L1 via MFMA: lane gets h1 dims {4g+r} and {16+4g+r} of its edge ----
    floatx4 h1lo = __builtin_amdgcn_mfma_f32_16x16x32_bf16(a1_0, bp, b1c0, 0, 0, 0);
    floatx4 h1hi = __builtin_amdgcn_mfma_f32_16x16x32_bf16(a1_1, bp, b1c1, 0, 0, 0);

    short8 bh1;   // slot j = h1[hperm(g,j)]
#pragma unroll
    for (int r = 0; r < 4; ++r) {
      bh1[r]     = f2bf(fmaxf(h1lo[r], 0.0f));
      bh1[4 + r] = f2bf(fmaxf(h1hi[r], 0.0f));
    }

    // ---- L2 via MFMA (b2 in C): lane gets h2 dims {4g+r},{16+4g+r} ----
    floatx4 h2lo = __builtin_amdgcn_mfma_f32_16x16x32_bf16(a2_0, bh1, b2c0, 0, 0, 0);
    floatx4 h2hi = __builtin_amdgcn_mfma_f32_16x16x32_bf16(a2_1, bh1, b2c1, 0, 0, 0);

    short8 bh2;   // slot j = h2[hperm(g,j)]
#pragma unroll
    for (int r = 0; r < 4; ++r) {
      bh2[r]     = f2bf(fmaxf(h2lo[r], 0.0f));
      bh2[4 + r] = f2bf(fmaxf(h2hi[r], 0.0f));
    }

    // ---- neighbor feature row (arrived by now) ----
    float f[16];
    f[0]=v0.x; f[1]=v0.y; f[2]=v0.z; f[3]=v0.w;
    f[4]=v1.x; f[5]=v1.y; f[6]=v1.z; f[7]=v1.w;
    f[8]=v2.x; f[9]=v2.y; f[10]=v2.z; f[11]=v2.w;
    f[12]=v3.x; f[13]=v3.y; f[14]=v3.z; f[15]=v3.w;

    // b3 term: D[o=4g+r, e=r16] = sum_i b3[i*16+o] f[e,i]  -> S init
    short8 af;
#pragma unroll
    for (int j = 0; j < 8; ++j) {
      float fv = (g == 0) ? f[j] : ((g == 1) ? f[8 + j] : 0.0f);
      af[j] = f2bf(fv);
    }
    floatx4 sb3 = __builtin_amdgcn_mfma_f32_16x16x32_bf16(bb, af, z4, 0, 0, 0);

    float S0 = sb3[0], S1 = sb3[1], S2 = sb3[2], S3 = sb3[3];
#pragma unroll
    for (int t = 0; t < 16; ++t) {
      floatx4 dd = __builtin_amdgcn_mfma_f32_16x16x32_bf16(bu[t], bh2, z4, 0, 0, 0);
      S0 = fmaf(f[t], dd[0], S0);
      S1 = fmaf(f[t], dd[1], S1);
      S2 = fmaf(f[t], dd[2], S2);
      S3 = fmaf(f[t], dd[3], S3);
    }

    // ---- segment sum over the 16 edge-lanes: DPP adds (VALU, no DS) ----
    S0 = dpp_add<0xB1>(S0); S1 = dpp_add<0xB1>(S1); S2 = dpp_add<0xB1>(S2); S3 = dpp_add<0xB1>(S3);
    S0 = dpp_add<0x4E>(S0); S1 = dpp_add<0x4E>(S1); S2 = dpp_add<0x4E>(S2); S3 = dpp_add<0x4E>(S3);
    S0 = dpp_add<0x124>(S0); S1 = dpp_add<0x124>(S1); S2 = dpp_add<0x124>(S2); S3 = dpp_add<0x124>(S3);
    S0 = dpp_add<0x128>(S0); S1 = dpp_add<0x128>(S1); S2 = dpp_add<0x128>(S2); S3 = dpp_add<0x128>(S3);

    if (r16 == 0) {
      float4 v = {S0, S1, S2, S3};
      *reinterpret_cast<float4*>(out + (size_t)q * 16 + 4 * g) = v;
    }
  }
}

extern "C" void kernel_launch(void* const* d_in, const int* in_sizes, int n_in,
                              void* d_out, int out_size, void* d_ws, size_t ws_size,
                              hipStream_t stream) {
  const float* feats = (const float*)d_in[0];
  const float* xyz   = (const float*)d_in[1];
  const int*   nbr   = (const int*)d_in[2];
  // d_in[3] = neighbors_row_splits: uniform arange*16 for this problem
  const float* dist  = (const float*)d_in[4];
  const float* W1 = (const float*)d_in[5];
  const float* b1 = (const float*)d_in[6];
  const float* W2 = (const float*)d_in[7];
  const float* b2 = (const float*)d_in[8];
  const float* W3 = (const float*)d_in[9];
  const float* b3 = (const float*)d_in[10];
  float* out = (float*)d_out;

  const int Nq = in_sizes[3] - 1;

  polarconv_v6<<<NBLOCKS, THREADS, 0, stream>>>(
      feats, xyz, nbr, dist, W1, b1, W2, b2, W3, b3, out, Nq);
}